// Round 10
// baseline (36.959 us; speedup 1.0000x reference)
//
#include <hip/hip_runtime.h>
#include <math.h>
#include <stdint.h>

#define N 2048
#define D 128
#define JS 16            // j-slices (and i-tiles): 16 x 16 blocks
#define BM 128           // i-rows per block
#define BN 128           // j-cols per block
#define NB 256           // blocks = JS*JS = one per CU
#define NT 512           // 8 waves

typedef __attribute__((ext_vector_type(8))) short bf16x8;
typedef __attribute__((ext_vector_type(4))) float f32x4;

// round-to-nearest-even fp32 -> bf16; also returns the bf16 value as fp32
__device__ __forceinline__ ushort f2bf(float x, float* back) {
    uint32_t u = __float_as_uint(x);
    uint32_t r = u + 0x7FFFu + ((u >> 16) & 1u);
    ushort hv = (ushort)(r >> 16);
    *back = __uint_as_float(((uint32_t)hv) << 16);
    return hv;
}

__device__ __forceinline__ unsigned long long packfi(float v, int i) {
    return ((unsigned long long)__float_as_uint(v) << 32) | (unsigned)i;
}

__global__ __launch_bounds__(NT) void fused_kernel(
    const float* __restrict__ q, const int* __restrict__ tgt,
    unsigned long long* __restrict__ wpos, unsigned long long* __restrict__ wneg,
    unsigned* __restrict__ cnt, unsigned* __restrict__ ticket2,
    unsigned* __restrict__ tp, float* __restrict__ out) {
    __shared__ ushort HJ[BN * D];  // 32 KB, XOR-swizzled rows (256 B/row)
    __shared__ ushort LJ[BN * D];  // 32 KB
    __shared__ float sni[BM];
    __shared__ float snj[BN];
    __shared__ int stj[BN];
    __shared__ float sred[8];
    __shared__ int sgo;

    const int b = blockIdx.x, ib = b >> 4, s = b & 15;
    const int i0 = ib * BM, j0 = s * BN;
    const int tid = threadIdx.x, w = tid >> 6, lane = tid & 63;
    const int lr = lane & 15, h = lane >> 4;
    const float4* q4 = reinterpret_cast<const float4*>(q);

    // ---- stage j-slice: fp32 -> (H,L) bf16 split into swizzled LDS + exact j-norms
    for (int c = tid; c < BN * 16; c += NT) {
        const int row = c >> 4, col = c & 15;
        float4 v0 = q4[(j0 + row) * 32 + col * 2];
        float4 v1 = q4[(j0 + row) * 32 + col * 2 + 1];
        float xs[8] = {v0.x, v0.y, v0.z, v0.w, v1.x, v1.y, v1.z, v1.w};
        uint hp[4], lp[4];
        float ss = 0.f;
#pragma unroll
        for (int e = 0; e < 4; ++e) {
            float hb0, hb1, d0, d1;
            ushort h0 = f2bf(xs[2 * e], &hb0);
            ushort h1 = f2bf(xs[2 * e + 1], &hb1);
            ushort l0 = f2bf(xs[2 * e] - hb0, &d0);
            ushort l1 = f2bf(xs[2 * e + 1] - hb1, &d1);
            hp[e] = (uint)h0 | ((uint)h1 << 16);
            lp[e] = (uint)l0 | ((uint)l1 << 16);
            ss = fmaf(xs[2 * e], xs[2 * e], ss);
            ss = fmaf(xs[2 * e + 1], xs[2 * e + 1], ss);
        }
        const int boff = row * 256 + ((col * 16) ^ ((row & 7) << 4));
        *reinterpret_cast<uint4*>((char*)HJ + boff) = make_uint4(hp[0], hp[1], hp[2], hp[3]);
        *reinterpret_cast<uint4*>((char*)LJ + boff) = make_uint4(lp[0], lp[1], lp[2], lp[3]);
        // the 16 granules of this row live in 16 consecutive lanes: butterfly-sum
        ss += __shfl_xor(ss, 1); ss += __shfl_xor(ss, 2);
        ss += __shfl_xor(ss, 4); ss += __shfl_xor(ss, 8);
        if ((tid & 15) == 0) snj[row] = ss;
    }
    if (tid < BN) stj[tid] = tgt[j0 + tid];

    // ---- A fragments in registers + exact i-norms (lane (lr,h) owns row rowbase+lr)
    const int rowbase = i0 + w * 16;
    bf16x8 AH[4], AL[4];
    float na = 0.f;
#pragma unroll
    for (int kk = 0; kk < 4; ++kk) {
        float4 u0 = q4[(rowbase + lr) * 32 + kk * 8 + h * 2];
        float4 u1 = q4[(rowbase + lr) * 32 + kk * 8 + h * 2 + 1];
        float xs[8] = {u0.x, u0.y, u0.z, u0.w, u1.x, u1.y, u1.z, u1.w};
#pragma unroll
        for (int e = 0; e < 8; ++e) {
            float hb, d_;
            ushort hv = f2bf(xs[e], &hb);
            ushort lv = f2bf(xs[e] - hb, &d_);
            AH[kk][e] = (short)hv;
            AL[kk][e] = (short)lv;
            na = fmaf(xs[e], xs[e], na);
        }
    }
    na += __shfl_xor(na, 16);  // lanes sharing lr hold disjoint col-slices
    na += __shfl_xor(na, 32);
    if (h == 0) sni[w * 16 + lr] = na;
    __syncthreads();

    float ni[4]; int ti[4];
#pragma unroll
    for (int m = 0; m < 4; ++m) {
        ni[m] = sni[w * 16 + h * 4 + m];
        ti[m] = tgt[rowbase + h * 4 + m];
    }
    float njr[8]; int tjr[8];
#pragma unroll
    for (int ct = 0; ct < 8; ++ct) {
        njr[ct] = snj[ct * 16 + lr];
        tjr[ct] = stj[ct * 16 + lr];
    }

    float bpv[4], bnv[4];
    int bpi[4], bni[4];
#pragma unroll
    for (int m = 0; m < 4; ++m) {
        bpv[m] = -INFINITY; bpi[m] = 0;
        bnv[m] = INFINITY;  bni[m] = 0;
    }

    // ---- MFMA pair scan over 8 column-tiles of 16 ----
    for (int ct = 0; ct < BN / 16; ++ct) {
        const int brow = ct * 16 + lr;
        const int bswz = (brow & 7) << 4;
        const char* hbase = (const char*)HJ + brow * 256;
        const char* lbase = (const char*)LJ + brow * 256;
        bf16x8 BH[4], BL[4];
#pragma unroll
        for (int kk = 0; kk < 4; ++kk) {
            int off = (kk * 64 + h * 16) ^ bswz;
            BH[kk] = *reinterpret_cast<const bf16x8*>(hbase + off);
            BL[kk] = *reinterpret_cast<const bf16x8*>(lbase + off);
        }
        // 4 independent accumulator chains (HH, HL, LH, LL) for ILP
        f32x4 a0 = (f32x4){0.f, 0.f, 0.f, 0.f};
        f32x4 a1 = (f32x4){0.f, 0.f, 0.f, 0.f};
        f32x4 a2 = (f32x4){0.f, 0.f, 0.f, 0.f};
        f32x4 a3 = (f32x4){0.f, 0.f, 0.f, 0.f};
#pragma unroll
        for (int kk = 0; kk < 4; ++kk) {
            a0 = __builtin_amdgcn_mfma_f32_16x16x32_bf16(AH[kk], BH[kk], a0, 0, 0, 0);
            a1 = __builtin_amdgcn_mfma_f32_16x16x32_bf16(AH[kk], BL[kk], a1, 0, 0, 0);
            a2 = __builtin_amdgcn_mfma_f32_16x16x32_bf16(AL[kk], BH[kk], a2, 0, 0, 0);
            a3 = __builtin_amdgcn_mfma_f32_16x16x32_bf16(AL[kk], BL[kk], a3, 0, 0, 0);
        }
        f32x4 acc = (a0 + a1) + (a2 + a3);

        const int jg = j0 + ct * 16 + lr;
#pragma unroll
        for (int m = 0; m < 4; ++m) {
            const int ig = rowbase + h * 4 + m;
            const float dist = fmaf(-2.f, acc[m], ni[m] + njr[ct]);
            const bool same = (ti[m] == tjr[ct]);
            const bool diag = (ig == jg);
            const float pmv = diag ? -INFINITY : (same ? dist : 0.f);
            if (pmv > bpv[m]) { bpv[m] = pmv; bpi[m] = jg; }
            const float nmv = (same || diag) ? INFINITY : dist;
            if (nmv < bnv[m]) { bnv[m] = nmv; bni[m] = jg; }
        }
    }

    // ---- merge across the 16 lanes sharing each C row (index tie-break) ----
#pragma unroll
    for (int mask = 1; mask <= 8; mask <<= 1) {
#pragma unroll
        for (int m = 0; m < 4; ++m) {
            float ov = __shfl_xor(bpv[m], mask);
            int oi = __shfl_xor(bpi[m], mask);
            if (ov > bpv[m] || (ov == bpv[m] && oi < bpi[m])) {
                bpv[m] = ov; bpi[m] = oi;
            }
            float onv = __shfl_xor(bnv[m], mask);
            int oni = __shfl_xor(bni[m], mask);
            if (onv < bnv[m] || (onv == bnv[m] && oni < bni[m])) {
                bnv[m] = onv; bni[m] = oni;
            }
        }
    }
    // ---- publish winners via coherent atomicExch (device-coherent point) ----
    if (lr == 0) {
        unsigned long long consume = 0ULL;
#pragma unroll
        for (int m = 0; m < 4; ++m) {
            int r = rowbase + h * 4 + m;
            int idx = r * JS + s;
            consume ^= atomicExch(&wpos[idx], packfi(bpv[m], bpi[m]));
            consume ^= atomicExch(&wneg[idx], packfi(bnv[m], bni[m]));
        }
        asm volatile("" : : "v"((unsigned)consume), "v"((unsigned)(consume >> 32)));
    }
    __syncthreads();  // barrier drains vmcnt for all waves: exchanges performed
    // exact-count ticket (cnt zeroed by the memset node each replay):
    // old == 15 identifies the TRUE 16th (last) arrival for this i-tile.
    if (tid == 0) sgo = (atomicAdd(&cnt[ib], 1u) == 15u) ? 1 : 0;
    __syncthreads();

    // ---- ticket-1 winner: finalize this i-tile's 128 rows (16 rows / wave) ----
    if (sgo) {
        const float2* q2 = reinterpret_cast<const float2*>(q);
        float wsum = 0.f;
#pragma unroll
        for (int pass = 0; pass < 4; ++pass) {
            // lane = (row-in-4)*16 + slice: one coherent read per (row, slice)
            const int ri = i0 + w * 16 + pass * 4 + h;  // h = row-in-4 here
            unsigned long long P = atomicAdd(&wpos[ri * JS + lr], 0ULL);
            unsigned long long G = atomicAdd(&wneg[ri * JS + lr], 0ULL);
            float pv = __uint_as_float((unsigned)(P >> 32));
            int pi = (int)(unsigned)P;
            float nv = __uint_as_float((unsigned)(G >> 32));
            int ng = (int)(unsigned)G;
#pragma unroll
            for (int mask = 1; mask <= 8; mask <<= 1) {
                float opv = __shfl_xor(pv, mask);
                int opi = __shfl_xor(pi, mask);
                if (opv > pv || (opv == pv && opi < pi)) { pv = opv; pi = opi; }
                float onv = __shfl_xor(nv, mask);
                int oni = __shfl_xor(ng, mask);
                if (onv < nv || (onv == nv && oni < ng)) { nv = onv; ng = oni; }
            }
#pragma unroll
            for (int rq = 0; rq < 4; ++rq) {
                const int i = i0 + w * 16 + pass * 4 + rq;
                int pib = __shfl(pi, rq * 16);  // merged winner of row rq
                int ngb = __shfl(ng, rq * 16);
                // clamp: insurance so no fault mode can ever core-dump
                pib = min(max(pib, 0), N - 1);
                ngb = min(max(ngb, 0), N - 1);
                // exact fp32 recompute, coalesced: 64 lanes x float2 = one 512B row
                float2 a = q2[i * (D / 2) + lane];
                float2 p = q2[pib * (D / 2) + lane];
                float2 g = q2[ngb * (D / 2) + lane];
                float dp = (a.x - p.x) * (a.x - p.x) + (a.y - p.y) * (a.y - p.y);
                float dn = (a.x - g.x) * (a.x - g.x) + (a.y - g.y) * (a.y - g.y);
#pragma unroll
                for (int mask = 1; mask <= 32; mask <<= 1) {
                    dp += __shfl_xor(dp, mask);
                    dn += __shfl_xor(dn, mask);
                }
                if (lane == 0) wsum += fmaxf(0.f, 1.0f - dp + dn);
            }
        }
        if (lane == 0) sred[w] = wsum;
        __syncthreads();
        if (tid == 0) {
            float bsum = 0.f;
#pragma unroll
            for (int k = 0; k < 8; ++k) bsum += sred[k];
            unsigned oldp = atomicExch(&tp[ib], __float_as_uint(bsum));
            asm volatile("" : : "v"(oldp) : "memory");  // partial performed first
            unsigned t2 = atomicAdd(ticket2, 1u);
            if (t2 == 15u) {  // TRUE last tile-finalizer: deterministic sum
                float tot = 0.f;
#pragma unroll
                for (int k = 0; k < JS; ++k)
                    tot += __uint_as_float(atomicAdd(&tp[k], 0u));
                out[0] = tot / (float)N;
            }
        }
    }
}

extern "C" void kernel_launch(void* const* d_in, const int* in_sizes, int n_in,
                              void* d_out, int out_size, void* d_ws, size_t ws_size,
                              hipStream_t stream) {
    const float* q = (const float*)d_in[0];
    const int* tgt = (const int*)d_in[1];

    unsigned* cnt = (unsigned*)d_ws;                         // 16 u32 (zeroed below)
    unsigned* ticket2 = cnt + 16;                            // 1 u32  (zeroed below)
    unsigned* tp = ticket2 + 1;                              // 16 u32 (atomicExch: no zero needed)
    unsigned long long* wpos = (unsigned long long*)((char*)d_ws + 256);  // N*JS u64
    unsigned long long* wneg = wpos + N * JS;                             // N*JS u64
    float* out = (float*)d_out;

    // memset node: zero the tickets on every graph replay (cheap, capturable)
    hipMemsetAsync(d_ws, 0, 256, stream);
    hipLaunchKernelGGL(fused_kernel, dim3(NB), dim3(NT), 0, stream,
                       q, tgt, wpos, wneg, cnt, ticket2, tp, out);
}

// Round 11
// 28.887 us; speedup vs baseline: 1.2794x; 1.2794x over previous
//
#include <hip/hip_runtime.h>
#include <math.h>
#include <stdint.h>

#define N 2048
#define D 128
#define JS 16            // j-slices (and i-tiles): 16 x 16 blocks
#define BM 128           // i-rows per block
#define BN 128           // j-cols per block
#define NB 256           // blocks = JS*JS = one per CU
#define NT 512           // 8 waves

typedef __attribute__((ext_vector_type(8))) short bf16x8;
typedef __attribute__((ext_vector_type(4))) float f32x4;

// round-to-nearest-even fp32 -> bf16; also returns the bf16 value as fp32
__device__ __forceinline__ ushort f2bf(float x, float* back) {
    uint32_t u = __float_as_uint(x);
    uint32_t r = u + 0x7FFFu + ((u >> 16) & 1u);
    ushort hv = (ushort)(r >> 16);
    *back = __uint_as_float(((uint32_t)hv) << 16);
    return hv;
}

__global__ __launch_bounds__(NT) void pair_kernel(
    const float* __restrict__ q, const int* __restrict__ tgt,
    float* __restrict__ wpv, int* __restrict__ wpi,
    float* __restrict__ wnv, int* __restrict__ wni,
    unsigned long long* __restrict__ sum_acc, unsigned* __restrict__ ticket) {
    __shared__ ushort HJ[BN * D];  // 32 KB, XOR-swizzled rows (256 B/row)
    __shared__ ushort LJ[BN * D];  // 32 KB
    __shared__ float sni[BM];
    __shared__ float snj[BN];
    __shared__ int stj[BN];

    const int b = blockIdx.x, ib = b >> 4, s = b & 15;
    const int i0 = ib * BM, j0 = s * BN;
    const int tid = threadIdx.x, w = tid >> 6, lane = tid & 63;
    const int lr = lane & 15, h = lane >> 4;
    const float4* q4 = reinterpret_cast<const float4*>(q);

    // Zero the accumulator AND the ticket for this call. The K1->K2 kernel
    // boundary publishes these device-wide, so K2's exact-count ticket
    // (old == 63) is correct on every replay regardless of ws poison.
    if (b == 0 && tid == 0) { *sum_acc = 0ULL; *ticket = 0u; }

    // ---- stage j-slice: fp32 -> (H,L) bf16 split into swizzled LDS + exact j-norms
    for (int c = tid; c < BN * 16; c += NT) {
        const int row = c >> 4, col = c & 15;
        float4 v0 = q4[(j0 + row) * 32 + col * 2];
        float4 v1 = q4[(j0 + row) * 32 + col * 2 + 1];
        float xs[8] = {v0.x, v0.y, v0.z, v0.w, v1.x, v1.y, v1.z, v1.w};
        uint hp[4], lp[4];
        float ss = 0.f;
#pragma unroll
        for (int e = 0; e < 4; ++e) {
            float hb0, hb1, d0, d1;
            ushort h0 = f2bf(xs[2 * e], &hb0);
            ushort h1 = f2bf(xs[2 * e + 1], &hb1);
            ushort l0 = f2bf(xs[2 * e] - hb0, &d0);
            ushort l1 = f2bf(xs[2 * e + 1] - hb1, &d1);
            hp[e] = (uint)h0 | ((uint)h1 << 16);
            lp[e] = (uint)l0 | ((uint)l1 << 16);
            ss = fmaf(xs[2 * e], xs[2 * e], ss);
            ss = fmaf(xs[2 * e + 1], xs[2 * e + 1], ss);
        }
        const int boff = row * 256 + ((col * 16) ^ ((row & 7) << 4));
        *reinterpret_cast<uint4*>((char*)HJ + boff) = make_uint4(hp[0], hp[1], hp[2], hp[3]);
        *reinterpret_cast<uint4*>((char*)LJ + boff) = make_uint4(lp[0], lp[1], lp[2], lp[3]);
        // the 16 granules of this row live in 16 consecutive lanes: butterfly-sum
        ss += __shfl_xor(ss, 1); ss += __shfl_xor(ss, 2);
        ss += __shfl_xor(ss, 4); ss += __shfl_xor(ss, 8);
        if ((tid & 15) == 0) snj[row] = ss;
    }
    if (tid < BN) stj[tid] = tgt[j0 + tid];

    // ---- A fragments in registers + exact i-norms (lane (lr,h) owns row rowbase+lr)
    const int rowbase = i0 + w * 16;
    bf16x8 AH[4], AL[4];
    float na = 0.f;
#pragma unroll
    for (int kk = 0; kk < 4; ++kk) {
        float4 u0 = q4[(rowbase + lr) * 32 + kk * 8 + h * 2];
        float4 u1 = q4[(rowbase + lr) * 32 + kk * 8 + h * 2 + 1];
        float xs[8] = {u0.x, u0.y, u0.z, u0.w, u1.x, u1.y, u1.z, u1.w};
#pragma unroll
        for (int e = 0; e < 8; ++e) {
            float hb, d_;
            ushort hv = f2bf(xs[e], &hb);
            ushort lv = f2bf(xs[e] - hb, &d_);
            AH[kk][e] = (short)hv;
            AL[kk][e] = (short)lv;
            na = fmaf(xs[e], xs[e], na);
        }
    }
    na += __shfl_xor(na, 16);  // lanes sharing lr hold disjoint col-slices
    na += __shfl_xor(na, 32);
    if (h == 0) sni[w * 16 + lr] = na;
    __syncthreads();

    float ni[4]; int ti[4];
#pragma unroll
    for (int m = 0; m < 4; ++m) {
        ni[m] = sni[w * 16 + h * 4 + m];
        ti[m] = tgt[rowbase + h * 4 + m];
    }
    float njr[8]; int tjr[8];
#pragma unroll
    for (int ct = 0; ct < 8; ++ct) {
        njr[ct] = snj[ct * 16 + lr];
        tjr[ct] = stj[ct * 16 + lr];
    }

    float bpv[4], bnv[4];
    int bpi[4], bni[4];
#pragma unroll
    for (int m = 0; m < 4; ++m) {
        bpv[m] = -INFINITY; bpi[m] = 0;
        bnv[m] = INFINITY;  bni[m] = 0;
    }

    // ---- MFMA pair scan over 8 column-tiles of 16 ----
    for (int ct = 0; ct < BN / 16; ++ct) {
        const int brow = ct * 16 + lr;
        const int bswz = (brow & 7) << 4;
        const char* hbase = (const char*)HJ + brow * 256;
        const char* lbase = (const char*)LJ + brow * 256;
        bf16x8 BH[4], BL[4];
#pragma unroll
        for (int kk = 0; kk < 4; ++kk) {
            int off = (kk * 64 + h * 16) ^ bswz;
            BH[kk] = *reinterpret_cast<const bf16x8*>(hbase + off);
            BL[kk] = *reinterpret_cast<const bf16x8*>(lbase + off);
        }
        // 4 independent accumulator chains (HH, HL, LH, LL) for ILP
        f32x4 a0 = (f32x4){0.f, 0.f, 0.f, 0.f};
        f32x4 a1 = (f32x4){0.f, 0.f, 0.f, 0.f};
        f32x4 a2 = (f32x4){0.f, 0.f, 0.f, 0.f};
        f32x4 a3 = (f32x4){0.f, 0.f, 0.f, 0.f};
#pragma unroll
        for (int kk = 0; kk < 4; ++kk) {
            a0 = __builtin_amdgcn_mfma_f32_16x16x32_bf16(AH[kk], BH[kk], a0, 0, 0, 0);
            a1 = __builtin_amdgcn_mfma_f32_16x16x32_bf16(AH[kk], BL[kk], a1, 0, 0, 0);
            a2 = __builtin_amdgcn_mfma_f32_16x16x32_bf16(AL[kk], BH[kk], a2, 0, 0, 0);
            a3 = __builtin_amdgcn_mfma_f32_16x16x32_bf16(AL[kk], BL[kk], a3, 0, 0, 0);
        }
        f32x4 acc = (a0 + a1) + (a2 + a3);

        const int jg = j0 + ct * 16 + lr;
#pragma unroll
        for (int m = 0; m < 4; ++m) {
            const int ig = rowbase + h * 4 + m;
            const float dist = fmaf(-2.f, acc[m], ni[m] + njr[ct]);
            const bool same = (ti[m] == tjr[ct]);
            const bool diag = (ig == jg);
            const float pmv = diag ? -INFINITY : (same ? dist : 0.f);
            if (pmv > bpv[m]) { bpv[m] = pmv; bpi[m] = jg; }
            const float nmv = (same || diag) ? INFINITY : dist;
            if (nmv < bnv[m]) { bnv[m] = nmv; bni[m] = jg; }
        }
    }

    // ---- merge across the 16 lanes sharing each C row (index tie-break) ----
#pragma unroll
    for (int mask = 1; mask <= 8; mask <<= 1) {
#pragma unroll
        for (int m = 0; m < 4; ++m) {
            float ov = __shfl_xor(bpv[m], mask);
            int oi = __shfl_xor(bpi[m], mask);
            if (ov > bpv[m] || (ov == bpv[m] && oi < bpi[m])) {
                bpv[m] = ov; bpi[m] = oi;
            }
            float onv = __shfl_xor(bnv[m], mask);
            int oni = __shfl_xor(bni[m], mask);
            if (onv < bnv[m] || (onv == bnv[m] && oni < bni[m])) {
                bnv[m] = onv; bni[m] = oni;
            }
        }
    }
    if (lr == 0) {
#pragma unroll
        for (int m = 0; m < 4; ++m) {
            int r = rowbase + h * 4 + m;
            int idx = r * JS + s;
            wpv[idx] = bpv[m]; wpi[idx] = bpi[m];
            wnv[idx] = bnv[m]; wni[idx] = bni[m];
        }
    }
}

// 64 blocks x 4 waves; wave handles 8 rows: slice merge + exact fp32 recompute.
// Mean via deterministic 2^32 fixed-point u64 atomics + exact-count ticket
// (sum_acc and ticket zeroed by pair_kernel each call; kernel boundary
// publishes the zeros, so old==63 identifies the TRUE last arrival).
__global__ __launch_bounds__(256) void finalize_kernel(
    const float* __restrict__ q, const float* __restrict__ wpv, const int* __restrict__ wpi,
    const float* __restrict__ wnv, const int* __restrict__ wni,
    unsigned long long* __restrict__ sum_acc, unsigned* __restrict__ ticket,
    float* __restrict__ out) {
    __shared__ float red[4];
    const int wave = threadIdx.x >> 6;
    const int lane = threadIdx.x & 63;
    const int l = lane & 15;
    const float2* q2 = reinterpret_cast<const float2*>(q);
    float lsum = 0.f;
#pragma unroll
    for (int r = 0; r < 8; ++r) {
        const int i = blockIdx.x * 32 + wave * 8 + r;
        // lane-parallel slice merge (all four 16-lane groups duplicate -> identical)
        float pv = wpv[i * JS + l];
        int pi = wpi[i * JS + l];
        float nv = wnv[i * JS + l];
        int ng = wni[i * JS + l];
#pragma unroll
        for (int mask = 1; mask <= 8; mask <<= 1) {
            float opv = __shfl_xor(pv, mask);
            int opi = __shfl_xor(pi, mask);
            if (opv > pv || (opv == pv && opi < pi)) { pv = opv; pi = opi; }
            float onv = __shfl_xor(nv, mask);
            int oni = __shfl_xor(ng, mask);
            if (onv < nv || (onv == nv && oni < ng)) { nv = onv; ng = oni; }
        }
        // clamp gather indices: pure insurance so no fault mode can core-dump
        pi = min(max(pi, 0), N - 1);
        ng = min(max(ng, 0), N - 1);
        // exact fp32 recompute, coalesced: 64 lanes x float2 = one 512B row
        float2 a = q2[i * (D / 2) + lane];
        float2 p = q2[pi * (D / 2) + lane];
        float2 g = q2[ng * (D / 2) + lane];
        float dp = (a.x - p.x) * (a.x - p.x) + (a.y - p.y) * (a.y - p.y);
        float dn = (a.x - g.x) * (a.x - g.x) + (a.y - g.y) * (a.y - g.y);
#pragma unroll
        for (int mask = 1; mask <= 32; mask <<= 1) {
            dp += __shfl_xor(dp, mask);
            dn += __shfl_xor(dn, mask);
        }
        if (lane == 0) lsum += fmaxf(0.f, 1.0f - dp + dn);
    }
    if (lane == 0) red[wave] = lsum;
    __syncthreads();
    if (threadIdx.x == 0) {
        float bsum = red[0] + red[1] + red[2] + red[3];
        unsigned long long fix = (unsigned long long)((double)bsum * 4294967296.0);
        unsigned long long old = atomicAdd(sum_acc, fix);
        // consume 'old' (forces vmcnt wait -> sum-add performed) and pin the
        // ticket add behind it ("memory" clobber stops reordering)
        asm volatile("" : : "v"((unsigned)old) : "memory");
        unsigned t = atomicAdd(ticket, 1u);
        if (t == 63u) {  // true last of 64 blocks: all sum-adds are in
            unsigned long long tot = atomicAdd(sum_acc, 0ULL);
            out[0] = (float)((double)tot / 4294967296.0 / (double)N);
        }
    }
}

extern "C" void kernel_launch(void* const* d_in, const int* in_sizes, int n_in,
                              void* d_out, int out_size, void* d_ws, size_t ws_size,
                              hipStream_t stream) {
    const float* q = (const float*)d_in[0];
    const int* tgt = (const int*)d_in[1];

    unsigned long long* sum_acc = (unsigned long long*)d_ws;  // 8 B, zeroed by K1
    unsigned* ticket = (unsigned*)((char*)d_ws + 8);          // zeroed by K1
    float* wpv = (float*)((char*)d_ws + 256);                 // N*JS
    int* wpi = (int*)(wpv + N * JS);                          // N*JS
    float* wnv = (float*)(wpi + N * JS);                      // N*JS
    int* wni = (int*)(wnv + N * JS);                          // N*JS
    float* out = (float*)d_out;

    hipLaunchKernelGGL(pair_kernel, dim3(NB), dim3(NT), 0, stream,
                       q, tgt, wpv, wpi, wnv, wni, sum_acc, ticket);
    hipLaunchKernelGGL(finalize_kernel, dim3(64), dim3(256), 0, stream,
                       q, wpv, wpi, wnv, wni, sum_acc, ticket, out);
}